// Round 13
// baseline (175.774 us; speedup 1.0000x reference)
//
#include <hip/hip_runtime.h>
#include <stdint.h>

#define B 4
#define T 256
#define V 1024
#define S 64
#define DIM 1024
#define CV 256

typedef __attribute__((ext_vector_type(8))) short bf16x8;
typedef __attribute__((ext_vector_type(4))) short s16x4;
typedef __attribute__((ext_vector_type(4))) float f32x4;

// ---- workspace layout, 4-byte word offsets; bf16 arrays counted in words ----
enum : int {
    WVT_O  = 0,                     // [1024*1024] bf16 Wv^T [d][e]   = 524288 w
    WUB_O  = WVT_O + 524288,        // [256*1024]  bf16 Wu [cv][e]    = 131072 w
    YB_O   = WUB_O + 131072,        // [1024*1024] bf16 y = x@Wk^T    = 524288 w
    WVPT_O = YB_O + 524288,         // [1024*256]  bf16 WvpT [d][cv]  = 131072 w
    WB_O   = WVPT_O + 131072,       // [1024*256]  bf16 W [bt][cv]    = 131072 w
    RS_O   = WB_O + 131072,         // [1024] f32 per-token sum of p
    PIDX_O = RS_O + B*T,            // [B*T*S] int selected v
    BV_O   = PIDX_O + B*T*S,        // [DIM] f32 bu@Wv (g_attn blk 320)
    BP_O   = BV_O + DIM,            // [16][1024] f32 bv partials (k1)
    WS_TOTAL = BP_O + 16*1024       // ~6 MB
};

__device__ __forceinline__ short f2bf(float f) {
    union { float f; unsigned u; } x; x.f = f;
    unsigned r = (x.u + 0x7FFF + ((x.u >> 16) & 1)) >> 16;
    return (short)r;
}
__device__ __forceinline__ float bf2f(short s) {
    union { unsigned u; float f; } x;
    x.u = ((unsigned)(unsigned short)s) << 16;
    return x.f;
}
__device__ __forceinline__ s16x4 cvt4(float4 f) {
    s16x4 o;
    o.x = f2bf(f.x); o.y = f2bf(f.y); o.z = f2bf(f.z); o.w = f2bf(f.w);
    return o;
}
// load 8 consecutive f32, round-convert to one bf16x8 MFMA fragment
__device__ __forceinline__ bf16x8 ld_cvt8(const float* __restrict__ p) {
    float4 f0 = *(const float4*)p;
    float4 f1 = *(const float4*)(p + 4);
    bf16x8 r;
    r[0] = f2bf(f0.x); r[1] = f2bf(f0.y); r[2] = f2bf(f0.z); r[3] = f2bf(f0.w);
    r[4] = f2bf(f1.x); r[5] = f2bf(f1.y); r[6] = f2bf(f1.z); r[7] = f2bf(f1.w);
    return r;
}

// ---- per-wave 32x32 MFMA tile from bf16 A[m][k] / Bt[n][k] (k-contig) ----
template<int K, int LDA, int LDB>
__device__ __forceinline__ void wave_mma(const short* __restrict__ A0,
                                         const short* __restrict__ B0,
                                         f32x4 acc[2][2]) {
    int lane = threadIdx.x & 63;
    int rw = lane & 15, q = lane >> 4;
    const short* ap0 = A0 + rw * LDA + q * 8;
    const short* ap1 = ap0 + 16 * LDA;
    const short* bp0 = B0 + rw * LDB + q * 8;
    const short* bp1 = bp0 + 16 * LDB;
#pragma unroll 4
    for (int kc = 0; kc < K; kc += 32) {
        bf16x8 a0 = *(const bf16x8*)(ap0 + kc);
        bf16x8 a1 = *(const bf16x8*)(ap1 + kc);
        bf16x8 b0 = *(const bf16x8*)(bp0 + kc);
        bf16x8 b1 = *(const bf16x8*)(bp1 + kc);
        acc[0][0] = __builtin_amdgcn_mfma_f32_16x16x32_bf16(a0, b0, acc[0][0], 0, 0, 0);
        acc[0][1] = __builtin_amdgcn_mfma_f32_16x16x32_bf16(a0, b1, acc[0][1], 0, 0, 0);
        acc[1][0] = __builtin_amdgcn_mfma_f32_16x16x32_bf16(a1, b0, acc[1][0], 0, 0, 0);
        acc[1][1] = __builtin_amdgcn_mfma_f32_16x16x32_bf16(a1, b1, acc[1][1], 0, 0, 0);
    }
}

// ================= k1: y GEMM + Wv transpose/bv + Wu convert + mask ===========
// blocks [0,256)    : y[bt,e] = x @ Wk^T, both natural f32 inline-cvt, 64x64/blk
// blocks [256,512)  : Wv transpose-convert -> WVT bf16 [d][e] + bv partials
// blocks [512,768)  : Wu f32 -> bf16
// blocks [768,832)  : mask compaction (self-detecting encoding)
__global__ void k1(const float* __restrict__ x, const float* __restrict__ Wk,
                   const float* __restrict__ Wv, const float* __restrict__ Wu,
                   const float* __restrict__ bu, const void* __restrict__ maskp,
                   float* __restrict__ ws, int* __restrict__ wsi) {
    __shared__ short smem[64 * 65];     // Wv-transpose tile (aliased by mask ints)
    __shared__ float tred[4 * 64];
    int blk = blockIdx.x, tid = threadIdx.x;
    int lane = tid & 63, wvi = tid >> 6;
    int rw = lane & 15, q = lane >> 4;

    if (blk < 256) {
        // ---- y GEMM: m = bt, n = e, K = d(1024); A = x, Bt = Wk, both natural
        int m0 = (blk >> 4) * 64, n0 = (blk & 15) * 64;
        int wm = (wvi >> 1) * 32, wn = (wvi & 1) * 32;
        const float* a0p = x + (size_t)(m0 + wm + rw) * DIM + q * 8;
        const float* a1p = a0p + 16 * DIM;
        const float* b0p = Wk + (size_t)(n0 + wn + rw) * DIM + q * 8;
        const float* b1p = b0p + 16 * DIM;
        f32x4 acc[2][2] = {};
#pragma unroll 4
        for (int kc = 0; kc < DIM; kc += 32) {
            bf16x8 a0 = ld_cvt8(a0p + kc);
            bf16x8 a1 = ld_cvt8(a1p + kc);
            bf16x8 b0 = ld_cvt8(b0p + kc);
            bf16x8 b1 = ld_cvt8(b1p + kc);
            acc[0][0] = __builtin_amdgcn_mfma_f32_16x16x32_bf16(a0, b0, acc[0][0], 0, 0, 0);
            acc[0][1] = __builtin_amdgcn_mfma_f32_16x16x32_bf16(a0, b1, acc[0][1], 0, 0, 0);
            acc[1][0] = __builtin_amdgcn_mfma_f32_16x16x32_bf16(a1, b0, acc[1][0], 0, 0, 0);
            acc[1][1] = __builtin_amdgcn_mfma_f32_16x16x32_bf16(a1, b1, acc[1][1], 0, 0, 0);
        }
        int col = lane & 15;
        short* yb = (short*)(ws + YB_O);
#pragma unroll
        for (int i = 0; i < 2; i++)
#pragma unroll
            for (int j = 0; j < 2; j++)
#pragma unroll
                for (int r = 0; r < 4; r++)
                    yb[(size_t)(m0 + wm + i * 16 + q * 4 + r) * DIM +
                       n0 + wn + j * 16 + col] = f2bf(acc[i][j][r]);
        return;
    }
    if (blk < 512) {
        // ---- Wv transpose-convert [e][d] -> [d][e] bf16 + bv partials ----
        int t2 = blk - 256;
        int e0 = (t2 >> 4) * 64, d0 = (t2 & 15) * 64;
        short* dst = (short*)(ws + WVT_O);
        int j = tid & 63, i0 = tid >> 6;
        float pb = 0.f;
#pragma unroll
        for (int p = 0; p < 16; p++) {
            int i = p * 4 + i0;
            float v = Wv[(size_t)(e0 + i) * DIM + d0 + j];
            smem[j * 65 + i] = f2bf(v);
            pb += bu[e0 + i] * v;
        }
        tred[i0 * 64 + j] = pb;
        __syncthreads();
#pragma unroll
        for (int p = 0; p < 16; p++) {
            int dd = p * 4 + i0;
            dst[(size_t)(d0 + dd) * DIM + e0 + j] = smem[dd * 65 + j];
        }
        if (i0 == 0) {
            float s = tred[j] + tred[64 + j] + tred[128 + j] + tred[192 + j];
            ws[BP_O + (e0 >> 6) * 1024 + d0 + j] = s;
        }
        return;
    }
    if (blk < 768) {
        // ---- Wu f32 -> bf16 (65536 float4) ----
        int i = (blk - 512) * 256 + tid;
        ((s16x4*)((short*)(ws + WUB_O)))[i] = cvt4(((const float4*)Wu)[i]);
        return;
    }
    // ---- mask compaction, blocks [768,832): single pass, 64-bit bitmask ----
    int* si = (int*)smem;   // [16][17] counts + 2 flags
    {
        int a = 0, bfl = 0;
        const uchar4* m4 = (const uchar4*)maskp;
#pragma unroll
        for (int jj = 0; jj < 4; jj++) {
            uchar4 u = m4[tid * 4 + jj];
            if (u.y | u.z | u.w) a = 1;
            if (u.x == 0x3f || u.y == 0x3f || u.z == 0x3f || u.w == 0x3f) bfl = 1;
        }
        if (tid == 0) { si[280] = 0; si[281] = 0; }
        __syncthreads();
        if (a) si[280] = 1;      // benign same-value race
        if (bfl) si[281] = 1;
        __syncthreads();
    }
    bool byteMode = si[280] && !si[281];
    int mb = blk - 768;
    int b = mb >> 4, tg = mb & 15;
    int tl = tid & 15, c = tid >> 4;
    int t = tg * 16 + tl;
    int v0 = c * 64;
    unsigned long long bits = 0ull;
    if (byteMode) {
        const uint8_t* m = (const uint8_t*)maskp + (size_t)(b * V + v0) * T + t;
#pragma unroll 8
        for (int j = 0; j < 64; j++)
            if (m[(size_t)j * T] != 0) bits |= 1ull << j;
    } else {
        const int* m = (const int*)maskp + (size_t)(b * V + v0) * T + t;
#pragma unroll 8
        for (int j = 0; j < 64; j++)
            if (m[(size_t)j * T] != 0) bits |= 1ull << j;
    }
    si[tl * 17 + c] = __popcll(bits);
    __syncthreads();
    int off = 0, total = 0;
#pragma unroll
    for (int cc = 0; cc < 16; cc++) {
        int cn = si[tl * 17 + cc];
        if (cc < c) off += cn;
        total += cn;
    }
    int base = PIDX_O + (b * T + t) * S;
    while (bits) {
        int j = __ffsll(bits) - 1;
        bits &= bits - 1;
        if (off < S) wsi[base + off] = v0 + j;
        off++;
    }
    if (c == 15)
        for (int j = (total < S ? total : S); j < S; j++) wsi[base + j] = 0;
}

// ========== k2: attention (blocks 0..255) + WvpT GEMM (256..319) + bv (320) ===
// Attention block = 4 bt. Phase 1: z[4][256] = y @ Wu^T via MFMA
// (B-frag = 4 y rows, cols 4..15 discarded), z -> LDS bf16.
// Phase 2 (wave = bt): c0 = y.bu; scores = gathered f32-vision rows . z (K=256);
// exp; RS; W bf16 = sum p * vision-row (f32 reads).
__global__ void k2(const float* __restrict__ vision, const float* __restrict__ bu,
                   float* __restrict__ ws, int* __restrict__ wsi) {
    __shared__ short zs[4][256];
    __shared__ int s_idx[4][64];
    __shared__ float s_ps[4][64];
    int tid = threadIdx.x, lane = tid & 63, wv = tid >> 6;
    int rw = lane & 15, q = lane >> 4;

    if (blockIdx.x >= 256) {
        if (blockIdx.x == 320) {       // ---- bv reduce ----
#pragma unroll
            for (int cch = 0; cch < 4; cch++) {
                int d = cch * 256 + tid;
                float s = 0.f;
#pragma unroll
                for (int g = 0; g < 16; g++) s += ws[BP_O + g * 1024 + d];
                ws[BV_O + d] = s;
            }
            return;
        }
        // ---- WvpT GEMM: Wvp^T[d][cv] from A=Wu, Bt=WvT; 256 wave-tiles ----
        int w = (blockIdx.x - 256) * 4 + wv;
        int m0 = (w >> 5) * 32, n0 = (w & 31) * 32;   // m: cv(256), n: d(1024)
        const short* A = (const short*)(ws + WUB_O) + (size_t)m0 * DIM;
        const short* Bt = (const short*)(ws + WVT_O) + (size_t)n0 * DIM;
        f32x4 acc[2][2] = {};
        wave_mma<DIM, DIM, DIM>(A, Bt, acc);
        int col = lane & 15;
        short* o = (short*)(ws + WVPT_O);
#pragma unroll
        for (int i = 0; i < 2; i++)
#pragma unroll
            for (int j = 0; j < 2; j++) {
                s16x4 v;
                v.x = f2bf(acc[i][j][0]); v.y = f2bf(acc[i][j][1]);
                v.z = f2bf(acc[i][j][2]); v.w = f2bf(acc[i][j][3]);
                *(s16x4*)&o[(size_t)(n0 + j * 16 + col) * CV + m0 + i * 16 + q * 4] = v;
            }
        return;
    }

    // ---- attention: block covers bt0..bt0+3 ----
    int bt0 = blockIdx.x * 4;
    int bt = bt0 + wv, b = bt >> 8;
    s_idx[wv][lane] = wsi[PIDX_O + bt * S + lane];    // S == 64, wave-local
    const short* yb = (const short*)(ws + YB_O);

    // phase 1: z tile; wave wv covers cv chunk [wv*64, +64)
    {
        const short* wub = (const short*)(ws + WUB_O);
        const short* bp = yb + (size_t)(bt0 + rw) * DIM + q * 8;  // rows 4..15 junk, discarded
#pragma unroll
        for (int tt = 0; tt < 4; tt++) {
            int m0 = wv * 64 + tt * 16;
            const short* ap = wub + (size_t)(m0 + rw) * DIM + q * 8;
            f32x4 a4 = {0.f, 0.f, 0.f, 0.f};
#pragma unroll 8
            for (int kc = 0; kc < DIM; kc += 32) {
                bf16x8 av = *(const bf16x8*)(ap + kc);
                bf16x8 bv = *(const bf16x8*)(bp + kc);
                a4 = __builtin_amdgcn_mfma_f32_16x16x32_bf16(av, bv, a4, 0, 0, 0);
            }
            int col = lane & 15;          // C col = B-row = bt-local
            if (col < 4) {
                s16x4 v;
                v.x = f2bf(a4[0]); v.y = f2bf(a4[1]);
                v.z = f2bf(a4[2]); v.w = f2bf(a4[3]);
                *(s16x4*)&zs[col][m0 + q * 4] = v;
            }
        }
    }
    __syncthreads();

    // phase 2: c0 = y[bt] . bu (bf16 y, f32 bu)
    float c0p = 0.f;
    const short* yr = yb + (size_t)bt * DIM;
#pragma unroll
    for (int j = 0; j < 4; j++) {
        s16x4 yv = *(const s16x4*)(yr + j * 256 + lane * 4);
        float4 b4 = *(const float4*)(bu + j * 256 + lane * 4);
        c0p += bf2f(yv.x) * b4.x + bf2f(yv.y) * b4.y +
               bf2f(yv.z) * b4.z + bf2f(yv.w) * b4.w;
    }
    for (int o = 32; o > 0; o >>= 1) c0p += __shfl_xor(c0p, o);
    float c0 = c0p;

    // scores: A = 16 gathered f32 vision rows (inline cvt), B = z broadcast
    const float* visb = vision + (size_t)b * V * CV;
    const short* zp = &zs[wv][q * 8];
    f32x4 acc[4] = {};
#pragma unroll
    for (int mt = 0; mt < 4; mt++) {
        const float* ap = visb + (size_t)s_idx[wv][mt * 16 + rw] * CV + q * 8;
        f32x4 a4 = {0.f, 0.f, 0.f, 0.f};
#pragma unroll
        for (int kc = 0; kc < CV; kc += 32) {
            bf16x8 av = ld_cvt8(ap + kc);
            bf16x8 bv = *(const bf16x8*)(zp + kc);
            a4 = __builtin_amdgcn_mfma_f32_16x16x32_bf16(av, bv, a4, 0, 0, 0);
        }
        acc[mt] = a4;
    }
    if (rw == 0) {     // C rows = q*4+r; all 16 cols identical
#pragma unroll
        for (int mt = 0; mt < 4; mt++)
#pragma unroll
            for (int r = 0; r < 4; r++)
                s_ps[wv][mt * 16 + q * 4 + r] = acc[mt][r];
    }
    float p = expf((s_ps[wv][lane] + c0) * 0.03125f);   // 1/sqrt(DIM)
    float rs = p;
    for (int o = 32; o > 0; o >>= 1) rs += __shfl_xor(rs, o);
    s_ps[wv][lane] = p;
    if (lane == 0) ws[RS_O + bt] = rs;

    // W accum from f32 vision rows: lane covers cv = lane*4..+3
    float4 wa = {0.f, 0.f, 0.f, 0.f};
#pragma unroll 8
    for (int s = 0; s < S; s++) {
        float pv = s_ps[wv][s];
        float4 vr = *(const float4*)(visb + (size_t)s_idx[wv][s] * CV + lane * 4);
        wa.x += pv * vr.x; wa.y += pv * vr.y;
        wa.z += pv * vr.z; wa.w += pv * vr.w;
    }
    s16x4 o;
    o.x = f2bf(wa.x); o.y = f2bf(wa.y); o.z = f2bf(wa.z); o.w = f2bf(wa.w);
    ((s16x4*)((short*)(ws + WB_O) + (size_t)bt * CV))[lane] = o;
}

// ---- g_out: out = x + (Wb @ WvpT^T + rs*bv)/denom; denom from RS reduce ----
__global__ void g_out_mfma(const float* __restrict__ x, float* __restrict__ ws,
                           float* __restrict__ out) {
    int w = blockIdx.x * 4 + (threadIdx.x >> 6);
    int m0 = (w >> 5) * 32, n0 = (w & 31) * 32;    // m: bt(1024), n: d(1024)
    int lane = threadIdx.x & 63;
    int b = m0 >> 8;
    float4 r4 = *(const float4*)(ws + RS_O + b * 256 + lane * 4);
    float dn = r4.x + r4.y + r4.z + r4.w;
    for (int o = 32; o > 0; o >>= 1) dn += __shfl_xor(dn, o);
    float inv = 1.0f / dn;
    const short* A = (const short*)(ws + WB_O) + (size_t)m0 * CV;
    const short* Bt = (const short*)(ws + WVPT_O) + (size_t)n0 * CV;
    f32x4 acc[2][2] = {};
    wave_mma<CV, CV, CV>(A, Bt, acc);
    int col = lane & 15, q = lane >> 4;
#pragma unroll
    for (int i = 0; i < 2; i++)
#pragma unroll
        for (int r = 0; r < 4; r++) {
            int row = m0 + i * 16 + q * 4 + r;
            float rs = ws[RS_O + row];
#pragma unroll
            for (int j = 0; j < 2; j++) {
                int cc = n0 + j * 16 + col;
                out[(size_t)row * DIM + cc] =
                    x[(size_t)row * DIM + cc] +
                    (acc[i][j][r] + rs * ws[BV_O + cc]) * inv;
            }
        }
}

extern "C" void kernel_launch(void* const* d_in, const int* in_sizes, int n_in,
                              void* d_out, int out_size, void* d_ws, size_t ws_size,
                              hipStream_t stream) {
    (void)in_sizes; (void)n_in; (void)out_size; (void)ws_size;
    const float* x      = (const float*)d_in[0];
    const float* vision = (const float*)d_in[1];
    const void*  mask   = d_in[2];
    const float* Wu     = (const float*)d_in[3];
    const float* bu     = (const float*)d_in[4];
    const float* Wk     = (const float*)d_in[5];
    const float* Wv     = (const float*)d_in[6];
    float* out = (float*)d_out;
    float* ws  = (float*)d_ws;
    int*   wsi = (int*)d_ws;

    k1<<<832, 256, 0, stream>>>(x, Wk, Wv, Wu, bu, mask, ws, wsi);
    k2<<<321, 256, 0, stream>>>(vision, bu, ws, wsi);
    g_out_mfma<<<256, 256, 0, stream>>>(x, ws, out);
}

// Round 14
// 167.878 us; speedup vs baseline: 1.0470x; 1.0470x over previous
//
#include <hip/hip_runtime.h>
#include <stdint.h>

#define B 4
#define T 256
#define V 1024
#define S 64
#define DIM 1024
#define CV 256

typedef __attribute__((ext_vector_type(8))) short bf16x8;
typedef __attribute__((ext_vector_type(4))) short s16x4;
typedef __attribute__((ext_vector_type(4))) float f32x4;

// ---- workspace layout, 4-byte word offsets; bf16 arrays counted in words ----
enum : int {
    WKPB_O = 0,                     // [256*1024]  bf16 Wkp  [cv][d]  = 131072 w
    WVPT_O = WKPB_O + 131072,       // [1024*256]  bf16 WvpT [d][cv]  = 131072 w
    XB_O   = WVPT_O + 131072,       // [1024*1024] bf16 x    [bt][d]  = 524288 w
    VB_O   = XB_O + 524288,         // [4096*256]  bf16 vision       = 524288 w
    WB_O   = VB_O + 524288,         // [1024*256]  bf16 W    [bt][cv] = 131072 w
    RS_O   = WB_O + 131072,         // [1024] f32 per-token sum of p
    PIDX_O = RS_O + B*T,            // [B*T*S] int selected v
    BK_O   = PIDX_O + B*T*S,        // [DIM] f32 bu@Wk (k1 m0==0 blocks)
    BV_O   = BK_O + DIM,            // [DIM] f32 bu@Wv
    WS_TOTAL = BV_O + DIM           // ~5.9 MB
};

#define LDSP 66                     // LDS row pitch (shorts): 132 B -> odd banks

__device__ __forceinline__ short f2bf(float f) {
    union { float f; unsigned u; } x; x.f = f;
    unsigned r = (x.u + 0x7FFF + ((x.u >> 16) & 1)) >> 16;
    return (short)r;
}
__device__ __forceinline__ float bf2f(short s) {
    union { unsigned u; float f; } x;
    x.u = ((unsigned)(unsigned short)s) << 16;
    return x.f;
}
__device__ __forceinline__ s16x4 cvt4(float4 f) {
    s16x4 o;
    o.x = f2bf(f.x); o.y = f2bf(f.y); o.z = f2bf(f.z); o.w = f2bf(f.w);
    return o;
}
__device__ __forceinline__ bf16x8 ld_cvt8(const float* __restrict__ p) {
    float4 f0 = *(const float4*)p;
    float4 f1 = *(const float4*)(p + 4);
    bf16x8 r;
    r[0] = f2bf(f0.x); r[1] = f2bf(f0.y); r[2] = f2bf(f0.z); r[3] = f2bf(f0.w);
    r[4] = f2bf(f1.x); r[5] = f2bf(f1.y); r[6] = f2bf(f1.z); r[7] = f2bf(f1.w);
    return r;
}

// ---- per-wave 32x32 MFMA tile from bf16 A[m][k] / Bt[n][k] (k-contig) ----
template<int K, int LDA, int LDB>
__device__ __forceinline__ void wave_mma(const short* __restrict__ A0,
                                         const short* __restrict__ B0,
                                         f32x4 acc[2][2]) {
    int lane = threadIdx.x & 63;
    int rw = lane & 15, q = lane >> 4;
    const short* ap0 = A0 + rw * LDA + q * 8;
    const short* ap1 = ap0 + 16 * LDA;
    const short* bp0 = B0 + rw * LDB + q * 8;
    const short* bp1 = bp0 + 16 * LDB;
#pragma unroll 4
    for (int kc = 0; kc < K; kc += 32) {
        bf16x8 a0 = *(const bf16x8*)(ap0 + kc);
        bf16x8 a1 = *(const bf16x8*)(ap1 + kc);
        bf16x8 b0 = *(const bf16x8*)(bp0 + kc);
        bf16x8 b1 = *(const bf16x8*)(bp1 + kc);
        acc[0][0] = __builtin_amdgcn_mfma_f32_16x16x32_bf16(a0, b0, acc[0][0], 0, 0, 0);
        acc[0][1] = __builtin_amdgcn_mfma_f32_16x16x32_bf16(a0, b1, acc[0][1], 0, 0, 0);
        acc[1][0] = __builtin_amdgcn_mfma_f32_16x16x32_bf16(a1, b0, acc[1][0], 0, 0, 0);
        acc[1][1] = __builtin_amdgcn_mfma_f32_16x16x32_bf16(a1, b1, acc[1][1], 0, 0, 0);
    }
}

// ================= k1: converts + weight GEMMs (from inputs) + mask ===========
// blocks [0,1024)    : vision f32 -> bf16
// blocks [1024,2048) : x f32 -> bf16
// blocks [2048,2176) : Wkp = Wu@Wk / WvpT = (Wu@Wv)^T, 64x64 tile per block,
//                      B transposed f32->bf16 through LDS per 64-K chunk;
//                      m-tile-0 blocks also emit bk/bv (full K in block).
// blocks [2176,2240) : mask compaction (self-detecting encoding)
__global__ void k1(const float* __restrict__ vision, const float* __restrict__ x,
                   const float* __restrict__ Wu, const float* __restrict__ Wk,
                   const float* __restrict__ Wv, const float* __restrict__ bu,
                   const void* __restrict__ maskp,
                   float* __restrict__ ws, int* __restrict__ wsi) {
    __shared__ short bl[64 * LDSP];     // transposed B chunk [d-local][e-local]
    __shared__ float tred[16 * 64];     // bias partials (m-tile-0 blocks)
    int blk = blockIdx.x, tid = threadIdx.x;
    int lane = tid & 63, wvi = tid >> 6;
    int rw = lane & 15, q = lane >> 4;

    if (blk < 2048) {   // ---- straight f32 -> bf16 converts ----
        const float* src; short* dst; int idx;
        if (blk < 1024) { src = vision; dst = (short*)(ws + VB_O); idx = blk; }
        else            { src = x;      dst = (short*)(ws + XB_O); idx = blk - 1024; }
        int i = idx * 256 + tid;
        ((s16x4*)dst)[i] = cvt4(((const float4*)src)[i]);
        return;
    }
    if (blk < 2176) {   // ---- weight GEMMs with LDS B-transpose ----
        int t2 = blk - 2048;
        int which = t2 >> 6, rem = t2 & 63;
        int m0 = (rem >> 4) * 64, n0 = (rem & 15) * 64;   // m: cv, n: d
        const float* Bsrc = which ? Wv : Wk;
        // per-thread fixed d-columns: d4 = (tid&15)*4; e = p*16 + (tid>>4)
        int d4 = (tid & 15) * 4, eg = tid >> 4;
        float4 pbv = {0.f, 0.f, 0.f, 0.f};
        int wm = (wvi >> 1) * 32, wn = (wvi & 1) * 32;
        const float* arow0 = Wu + (size_t)(m0 + wm + rw) * DIM;
        const float* arow1 = arow0 + (size_t)16 * DIM;
        f32x4 acc[2][2] = {};
        for (int kc0 = 0; kc0 < DIM; kc0 += 64) {
            // stage B chunk [64 e][64 d] -> bl[d][e] bf16
#pragma unroll
            for (int p = 0; p < 4; p++) {
                int e = p * 16 + eg;
                float4 w = *(const float4*)(Bsrc + (size_t)(kc0 + e) * DIM + n0 + d4);
                bl[(d4 + 0) * LDSP + e] = f2bf(w.x);
                bl[(d4 + 1) * LDSP + e] = f2bf(w.y);
                bl[(d4 + 2) * LDSP + e] = f2bf(w.z);
                bl[(d4 + 3) * LDSP + e] = f2bf(w.w);
                if (m0 == 0) {
                    float bue = bu[kc0 + e];
                    pbv.x += bue * w.x; pbv.y += bue * w.y;
                    pbv.z += bue * w.z; pbv.w += bue * w.w;
                }
            }
            __syncthreads();
            // MFMA over the chunk: A = Wu f32 inline-cvt (read-once weight)
#pragma unroll
            for (int kc = 0; kc < 64; kc += 32) {
                bf16x8 a0 = ld_cvt8(arow0 + kc0 + kc + q * 8);
                bf16x8 a1 = ld_cvt8(arow1 + kc0 + kc + q * 8);
                bf16x8 b0 = *(const bf16x8*)&bl[(wn + rw) * LDSP + kc + q * 8];
                bf16x8 b1 = *(const bf16x8*)&bl[(wn + 16 + rw) * LDSP + kc + q * 8];
                acc[0][0] = __builtin_amdgcn_mfma_f32_16x16x32_bf16(a0, b0, acc[0][0], 0, 0, 0);
                acc[0][1] = __builtin_amdgcn_mfma_f32_16x16x32_bf16(a0, b1, acc[0][1], 0, 0, 0);
                acc[1][0] = __builtin_amdgcn_mfma_f32_16x16x32_bf16(a1, b0, acc[1][0], 0, 0, 0);
                acc[1][1] = __builtin_amdgcn_mfma_f32_16x16x32_bf16(a1, b1, acc[1][1], 0, 0, 0);
            }
            __syncthreads();
        }
        // bias finalize (m-tile 0 holds full K): reduce 16 e-groups per d
        if (m0 == 0) {
            tred[eg * 64 + d4 + 0] = pbv.x;
            tred[eg * 64 + d4 + 1] = pbv.y;
            tred[eg * 64 + d4 + 2] = pbv.z;
            tred[eg * 64 + d4 + 3] = pbv.w;
            __syncthreads();
            if (tid < 64) {
                float s = 0.f;
#pragma unroll
                for (int g = 0; g < 16; g++) s += tred[g * 64 + tid];
                ws[(which ? BV_O : BK_O) + n0 + tid] = s;
            }
        }
        // store C
        int col = lane & 15;
        if (which == 0) {   // Wkp[cv][d]
            short* o = (short*)(ws + WKPB_O);
#pragma unroll
            for (int i = 0; i < 2; i++)
#pragma unroll
                for (int j = 0; j < 2; j++)
#pragma unroll
                    for (int r = 0; r < 4; r++)
                        o[(size_t)(m0 + wm + i * 16 + q * 4 + r) * DIM +
                          n0 + wn + j * 16 + col] = f2bf(acc[i][j][r]);
        } else {            // WvpT[d][cv]
            short* o = (short*)(ws + WVPT_O);
#pragma unroll
            for (int i = 0; i < 2; i++)
#pragma unroll
                for (int j = 0; j < 2; j++) {
                    s16x4 v;
                    v.x = f2bf(acc[i][j][0]); v.y = f2bf(acc[i][j][1]);
                    v.z = f2bf(acc[i][j][2]); v.w = f2bf(acc[i][j][3]);
                    *(s16x4*)&o[(size_t)(n0 + wn + j * 16 + col) * CV +
                                m0 + wm + i * 16 + q * 4] = v;
                }
        }
        return;
    }
    // ---- mask compaction, blocks [2176,2240) ----
    int* si = (int*)bl;     // [16][17] counts + 2 flags
    {
        int a = 0, bfl = 0;
        const uchar4* m4 = (const uchar4*)maskp;
#pragma unroll
        for (int jj = 0; jj < 4; jj++) {
            uchar4 u = m4[tid * 4 + jj];
            if (u.y | u.z | u.w) a = 1;
            if (u.x == 0x3f || u.y == 0x3f || u.z == 0x3f || u.w == 0x3f) bfl = 1;
        }
        if (tid == 0) { si[280] = 0; si[281] = 0; }
        __syncthreads();
        if (a) si[280] = 1;          // benign same-value race
        if (bfl) si[281] = 1;
        __syncthreads();
    }
    bool byteMode = si[280] && !si[281];
    int mb = blk - 2176;
    int b = mb >> 4, tg = mb & 15;
    int tl = tid & 15, c = tid >> 4;
    int t = tg * 16 + tl;
    int v0 = c * 64;
    unsigned long long bits = 0ull;
    if (byteMode) {
        const uint8_t* m = (const uint8_t*)maskp + (size_t)(b * V + v0) * T + t;
#pragma unroll 8
        for (int j = 0; j < 64; j++)
            if (m[(size_t)j * T] != 0) bits |= 1ull << j;
    } else {
        const int* m = (const int*)maskp + (size_t)(b * V + v0) * T + t;
#pragma unroll 8
        for (int j = 0; j < 64; j++)
            if (m[(size_t)j * T] != 0) bits |= 1ull << j;
    }
    si[tl * 17 + c] = __popcll(bits);
    __syncthreads();
    int off = 0, total = 0;
#pragma unroll
    for (int cc = 0; cc < 16; cc++) {
        int cn = si[tl * 17 + cc];
        if (cc < c) off += cn;
        total += cn;
    }
    int base = PIDX_O + (b * T + t) * S;
    while (bits) {
        int j = __ffsll(bits) - 1;
        bits &= bits - 1;
        if (off < S) wsi[base + off] = v0 + j;
        off++;
    }
    if (c == 15)
        for (int j = (total < S ? total : S); j < S; j++) wsi[base + j] = 0;
}

// ---- g_attn (verbatim R12): block = 4 bt. Phase 1: z[4][256] = xb @ Wkp^T via
// ---- MFMA (B-frag = 4 xb rows, cols 4..15 discarded), z -> LDS bf16.
// ---- Phase 2 (wave = bt): c0 = x.bk; scores = gathered VB rows . z (K=256);
// ---- exp; RS; W bf16 = sum p*vis_row. ----
__global__ void g_attn(const float* __restrict__ x, float* __restrict__ ws,
                       int* __restrict__ wsi) {
    __shared__ short zs[4][256];
    __shared__ int s_idx[4][64];
    __shared__ float s_ps[4][64];
    int tid = threadIdx.x, lane = tid & 63, wv = tid >> 6;
    int bt0 = blockIdx.x * 4;
    int bt = bt0 + wv, b = bt >> 8;
    int rw = lane & 15, q = lane >> 4;
    s_idx[wv][lane] = wsi[PIDX_O + bt * S + lane];

    {   // phase 1: z tile; wave wv covers cv chunk [wv*64, +64)
        const short* xb = (const short*)(ws + XB_O);
        const short* wkp = (const short*)(ws + WKPB_O);
        const short* bp = xb + (size_t)(bt0 + rw) * DIM + q * 8;
#pragma unroll
        for (int tt = 0; tt < 4; tt++) {
            int m0 = wv * 64 + tt * 16;
            const short* ap = wkp + (size_t)(m0 + rw) * DIM + q * 8;
            f32x4 a4 = {0.f, 0.f, 0.f, 0.f};
#pragma unroll 8
            for (int kc = 0; kc < DIM; kc += 32) {
                bf16x8 av = *(const bf16x8*)(ap + kc);
                bf16x8 bv = *(const bf16x8*)(bp + kc);
                a4 = __builtin_amdgcn_mfma_f32_16x16x32_bf16(av, bv, a4, 0, 0, 0);
            }
            int col = lane & 15;
            if (col < 4) {
                s16x4 v;
                v.x = f2bf(a4[0]); v.y = f2bf(a4[1]);
                v.z = f2bf(a4[2]); v.w = f2bf(a4[3]);
                *(s16x4*)&zs[col][m0 + q * 4] = v;
            }
        }
    }
    __syncthreads();

    // phase 2: c0 = x[bt].bk (f32)
    float c0p = 0.f;
    const float4* xr = (const float4*)(x + (size_t)bt * DIM);
    const float4* bkr = (const float4*)(ws + BK_O);
#pragma unroll
    for (int j = 0; j < 4; j++) {
        float4 a = xr[lane + 64 * j], k4 = bkr[lane + 64 * j];
        c0p += a.x * k4.x + a.y * k4.y + a.z * k4.z + a.w * k4.w;
    }
    for (int o = 32; o > 0; o >>= 1) c0p += __shfl_xor(c0p, o);
    float c0 = c0p;
    // scores: A = 16 gathered bf16 vision rows, B = z broadcast
    const short* vb = (const short*)(ws + VB_O) + (size_t)b * V * CV;
    const short* zp = &zs[wv][q * 8];
    f32x4 acc[4] = {};
#pragma unroll
    for (int mt = 0; mt < 4; mt++) {
        const short* ap = vb + (size_t)s_idx[wv][mt * 16 + rw] * CV + q * 8;
        f32x4 a4 = {0.f, 0.f, 0.f, 0.f};
#pragma unroll
        for (int kc = 0; kc < CV; kc += 32) {
            bf16x8 av = *(const bf16x8*)(ap + kc);
            bf16x8 bv = *(const bf16x8*)(zp + kc);
            a4 = __builtin_amdgcn_mfma_f32_16x16x32_bf16(av, bv, a4, 0, 0, 0);
        }
        acc[mt] = a4;
    }
    if (rw == 0) {
#pragma unroll
        for (int mt = 0; mt < 4; mt++)
#pragma unroll
            for (int r = 0; r < 4; r++)
                s_ps[wv][mt * 16 + q * 4 + r] = acc[mt][r];
    }
    float p = expf((s_ps[wv][lane] + c0) * 0.03125f);
    float rs = p;
    for (int o = 32; o > 0; o >>= 1) rs += __shfl_xor(rs, o);
    s_ps[wv][lane] = p;
    if (lane == 0) ws[RS_O + bt] = rs;
    // W accum from bf16 vision rows
    float4 wa = {0.f, 0.f, 0.f, 0.f};
#pragma unroll 8
    for (int s = 0; s < S; s++) {
        float pv = s_ps[wv][s];
        s16x4 r4 = *(const s16x4*)(vb + (size_t)s_idx[wv][s] * CV + lane * 4);
        wa.x += pv * bf2f(r4.x); wa.y += pv * bf2f(r4.y);
        wa.z += pv * bf2f(r4.z); wa.w += pv * bf2f(r4.w);
    }
    s16x4 o;
    o.x = f2bf(wa.x); o.y = f2bf(wa.y); o.z = f2bf(wa.z); o.w = f2bf(wa.w);
    ((s16x4*)((short*)(ws + WB_O) + (size_t)bt * CV))[lane] = o;
}

// ---- g_out (verbatim R12): out = x + (Wb @ WvpT^T + rs*bv)/denom ----
__global__ void g_out_mfma(const float* __restrict__ x, float* __restrict__ ws,
                           float* __restrict__ out) {
    int w = blockIdx.x * 4 + (threadIdx.x >> 6);
    int m0 = (w >> 5) * 32, n0 = (w & 31) * 32;
    int lane = threadIdx.x & 63;
    int b = m0 >> 8;
    float4 r4 = *(const float4*)(ws + RS_O + b * 256 + lane * 4);
    float dn = r4.x + r4.y + r4.z + r4.w;
    for (int o = 32; o > 0; o >>= 1) dn += __shfl_xor(dn, o);
    float inv = 1.0f / dn;
    const short* A = (const short*)(ws + WB_O) + (size_t)m0 * CV;
    const short* Bt = (const short*)(ws + WVPT_O) + (size_t)n0 * CV;
    f32x4 acc[2][2] = {};
    wave_mma<CV, CV, CV>(A, Bt, acc);
    int col = lane & 15, q = lane >> 4;
#pragma unroll
    for (int i = 0; i < 2; i++)
#pragma unroll
        for (int r = 0; r < 4; r++) {
            int row = m0 + i * 16 + q * 4 + r;
            float rs = ws[RS_O + row];
#pragma unroll
            for (int j = 0; j < 2; j++) {
                int cc = n0 + j * 16 + col;
                out[(size_t)row * DIM + cc] =
                    x[(size_t)row * DIM + cc] +
                    (acc[i][j][r] + rs * ws[BV_O + cc]) * inv;
            }
        }
}

extern "C" void kernel_launch(void* const* d_in, const int* in_sizes, int n_in,
                              void* d_out, int out_size, void* d_ws, size_t ws_size,
                              hipStream_t stream) {
    (void)in_sizes; (void)n_in; (void)out_size; (void)ws_size;
    const float* x      = (const float*)d_in[0];
    const float* vision = (const float*)d_in[1];
    const void*  mask   = d_in[2];
    const float* Wu     = (const float*)d_in[3];
    const float* bu     = (const float*)d_in[4];
    const float* Wk     = (const float*)d_in[5];
    const float* Wv     = (const float*)d_in[6];
    float* out = (float*)d_out;
    float* ws  = (float*)d_ws;
    int*   wsi = (int*)d_ws;

    k1<<<2240, 256, 0, stream>>>(vision, x, Wu, Wk, Wv, bu, mask, ws, wsi);
    g_attn<<<256, 256, 0, stream>>>(x, ws, wsi);
    g_out_mfma<<<256, 256, 0, stream>>>(x, ws, out);
}